// Round 12
// baseline (259.844 us; speedup 1.0000x reference)
//
#include <hip/hip_runtime.h>
#include <cstdint>

// Problem constants
#define T_DIM 8192
#define D_DIM 1024
#define NB_DIM 64
#define QKS 2048  // row stride of fused q|k buffer

typedef __bf16 bf16x8 __attribute__((ext_vector_type(8)));
typedef __bf16 bf16x4 __attribute__((ext_vector_type(4)));
typedef float f32x4 __attribute__((ext_vector_type(4)));

#define MFMA16(a, b, c) __builtin_amdgcn_mfma_f32_16x16x32_bf16((a), (b), (c), 0, 0, 0)
#define BAR() asm volatile("s_barrier" ::: "memory")
#define VMCNT(n) asm volatile("s_waitcnt vmcnt(" #n ")" ::: "memory")

// async global->LDS, 16B per lane. LDS dest must be wave-uniform base + lane*16.
__device__ __forceinline__ void gld_lds16(const void* gsrc, void* ldst) {
  __builtin_amdgcn_global_load_lds(
      (__attribute__((address_space(1))) void*)(uintptr_t)gsrc,
      (__attribute__((address_space(3))) void*)(uintptr_t)ldst,
      16, 0, 0);
}

// ---------------------------------------------------------------------------
// Batched weight convert+transpose: 6 jobs in ONE launch (8192 blocks).
// ---------------------------------------------------------------------------
__global__ __launch_bounds__(256) void transpose_all(
    const float* __restrict__ wq, const float* __restrict__ wk,
    const float* __restrict__ wv, const float* __restrict__ wo,
    const float* __restrict__ wg, const float* __restrict__ wd,
    __bf16* __restrict__ wqkT, __bf16* __restrict__ wvT,
    __bf16* __restrict__ woT, __bf16* __restrict__ wgT,
    __bf16* __restrict__ wdT) {
  __shared__ float tile[32][33];
  const int bid = (int)blockIdx.x;
  const float* W; __bf16* Wt; int K, N, n0, k0, local;
  if (bid < 1024)      { W = wq; Wt = wqkT;            K = 1024; N = 1024; local = bid; }
  else if (bid < 2048) { W = wk; Wt = wqkT + 1048576;  K = 1024; N = 1024; local = bid - 1024; }
  else if (bid < 3072) { W = wv; Wt = wvT;             K = 1024; N = 1024; local = bid - 2048; }
  else if (bid < 4096) { W = wo; Wt = woT;             K = 1024; N = 1024; local = bid - 3072; }
  else if (bid < 6144) { W = wg; Wt = wgT;             K = 1024; N = 2048; local = bid - 4096; }
  else                 { W = wd; Wt = wdT;             K = 2048; N = 1024; local = bid - 6144; }
  if (N == 2048) { n0 = (local & 63) * 32; k0 = (local >> 6) * 32; }
  else           { n0 = (local & 31) * 32; k0 = (local >> 5) * 32; }
  const int tx = threadIdx.x & 31, ty = threadIdx.x >> 5;
#pragma unroll
  for (int i = 0; i < 32; i += 8)
    tile[ty + i][tx] = W[(size_t)(k0 + ty + i) * N + n0 + tx];
  __syncthreads();
#pragma unroll
  for (int i = 0; i < 32; i += 8)
    Wt[(size_t)(n0 + ty + i) * K + k0 + tx] = (__bf16)tile[tx][ty + i];
}

// ---------------------------------------------------------------------------
// LayerNorm: x[row][1024] (f32 or bf16) -> out bf16. One block (256) per row.
// ---------------------------------------------------------------------------
template <typename TI>
__global__ __launch_bounds__(256) void ln_kernel(
    const TI* __restrict__ x, const float* __restrict__ g,
    const float* __restrict__ b, __bf16* __restrict__ out) {
  __shared__ float red[8];
  const int row = blockIdx.x, tid = threadIdx.x;
  float v0, v1, v2, v3;
  if constexpr (sizeof(TI) == 4) {
    const float4 v = ((const float4*)(x + (size_t)row * D_DIM))[tid];
    v0 = v.x; v1 = v.y; v2 = v.z; v3 = v.w;
  } else {
    const bf16x4 v = ((const bf16x4*)(x + (size_t)row * D_DIM))[tid];
    v0 = (float)v[0]; v1 = (float)v[1]; v2 = (float)v[2]; v3 = (float)v[3];
  }
  float s = v0 + v1 + v2 + v3;
#pragma unroll
  for (int off = 32; off >= 1; off >>= 1) s += __shfl_xor(s, off, 64);
  if ((tid & 63) == 0) red[tid >> 6] = s;
  __syncthreads();
  const float mean = (red[0] + red[1] + red[2] + red[3]) * (1.0f / D_DIM);
  const float d0 = v0 - mean, d1 = v1 - mean, d2 = v2 - mean, d3 = v3 - mean;
  float ss = d0 * d0 + d1 * d1 + d2 * d2 + d3 * d3;
#pragma unroll
  for (int off = 32; off >= 1; off >>= 1) ss += __shfl_xor(ss, off, 64);
  if ((tid & 63) == 0) red[4 + (tid >> 6)] = ss;
  __syncthreads();
  const float var = (red[4] + red[5] + red[6] + red[7]) * (1.0f / D_DIM);
  const float rstd = rsqrtf(var + 1e-5f);
  const float4 gg = ((const float4*)g)[tid];
  const float4 bb = ((const float4*)b)[tid];
  bf16x4 o;
  o[0] = (__bf16)(d0 * rstd * gg.x + bb.x);
  o[1] = (__bf16)(d1 * rstd * gg.y + bb.y);
  o[2] = (__bf16)(d2 * rstd * gg.z + bb.z);
  o[3] = (__bf16)(d3 * rstd * gg.w + bb.w);
  *(bf16x4*)(out + (size_t)row * D_DIM + tid * 4) = o;
}

// ---------------------------------------------------------------------------
// 2-phase GEMM (m97 structure) — V projection with transposed output.
// ---------------------------------------------------------------------------
__global__ __launch_bounds__(256, 2) void gemm_vt(
    const __bf16* __restrict__ A, const __bf16* __restrict__ Bt,
    __bf16* __restrict__ Cout, int M, int N, int K) {
  __shared__ __bf16 smem[32768];
  __bf16* As = smem;
  __bf16* Bs = smem + 16384;
  const int tid = threadIdx.x;
  const int l = tid & 63, w = tid >> 6;
  const int lr = l & 15, lg = l >> 4;
  const int wr = w >> 1, wc = w & 1;
  const int bm = blockIdx.y, bn = blockIdx.x;
  const size_t arow0 = (size_t)bm * 128;
  const size_t brow0 = (size_t)bn * 128;

  f32x4 acc[4][4];
  const f32x4 z4 = {0.f, 0.f, 0.f, 0.f};
#pragma unroll
  for (int m = 0; m < 4; ++m)
#pragma unroll
    for (int n = 0; n < 4; ++n) acc[m][n] = z4;

  auto stage = [&](int buf, int k0) {
#pragma unroll
    for (int r = 0; r < 4; ++r) {
      int ci = r * 256 + tid;
      int row = ci >> 3, c8 = ci & 7;
      gld_lds16(A + (arow0 + row) * K + k0 + c8 * 8, &As[buf * 8192 + ci * 8]);
    }
#pragma unroll
    for (int r = 0; r < 4; ++r) {
      int ci = r * 256 + tid;
      int row = ci >> 3, c8 = ci & 7;
      gld_lds16(Bt + (brow0 + row) * K + k0 + c8 * 8, &Bs[buf * 8192 + ci * 8]);
    }
  };

  stage(0, 0);
  const int nk = K >> 6;
  int cur = 0;
  __syncthreads();

  for (int t = 0; t < nk; ++t) {
    if (t + 1 < nk) stage(cur ^ 1, (t + 1) << 6);
#pragma unroll
    for (int kk = 0; kk < 2; ++kk) {
      bf16x8 af[4], bf_[4];
#pragma unroll
      for (int m = 0; m < 4; ++m)
        af[m] = *(const bf16x8*)&As[cur * 8192 + (wr * 64 + m * 16 + lr) * 64 + kk * 32 + lg * 8];
#pragma unroll
      for (int n = 0; n < 4; ++n)
        bf_[n] = *(const bf16x8*)&Bs[cur * 8192 + (wc * 64 + n * 16 + lr) * 64 + kk * 32 + lg * 8];
#pragma unroll
      for (int m = 0; m < 4; ++m)
#pragma unroll
        for (int n = 0; n < 4; ++n) acc[m][n] = MFMA16(af[m], bf_[n], acc[m][n]);
    }
    __syncthreads();
    cur ^= 1;
  }

  // Transposed bf16 store via LDS: Tt[c(128)][136].
  __bf16* Tt = smem;
#pragma unroll
  for (int m = 0; m < 4; ++m)
#pragma unroll
    for (int n = 0; n < 4; ++n)
#pragma unroll
      for (int r = 0; r < 4; ++r)
        Tt[(wc * 64 + n * 16 + lr) * 136 + wr * 64 + m * 16 + lg * 4 + r] =
            (__bf16)acc[m][n][r];
  __syncthreads();
#pragma unroll
  for (int i = 0; i < 8; ++i) {
    const int ci = i * 256 + tid;
    const int c = ci >> 4;
    const int rr = (ci & 15) * 8;
    const bf16x8 vv = *(const bf16x8*)&Tt[c * 136 + rr];
    *(bf16x8*)(Cout + (size_t)(bn * 128 + c) * M + bm * 128 + rr) = vv;
  }
}

// ---------------------------------------------------------------------------
// gemm8 (BM=128 proven config) with OUTPUT STRIDE ldc — all GEMMs now run at
// N=1024 per launch (nbn=4) so each XCD's working set (B 2MB + A 2MB) fits
// its 4MB L2. Split outputs (q|k, gate halves) write into a wider buffer via
// ldc. Schedule: single-barrier 4 phases, t+2 staggered staging, counted
// vmcnt gates (R9/R10, verified). T2 XOR swizzle both-sides.
// EPI: 0 bf16; 3 silu->bf16; 4 +Res(f32)->bf16; 5 +Res(bf16)->f32.
// Res is indexed [row][ldc_res] where ldc_res == 1024 always here (D_DIM).
// ---------------------------------------------------------------------------
template <int EPI>
__global__ __launch_bounds__(512, 2) void gemm8(
    const __bf16* __restrict__ A, const __bf16* __restrict__ Bt,
    const void* __restrict__ Res, void* __restrict__ Cout,
    int M, int K, int nbn, int ldc) {
  constexpr int BM_ = 128;
  constexpr int MF = BM_ / 32;      // 4 m-frags per wave
  constexpr int MH = MF / 2;        // 2
  constexpr int SA = 8 * MF;        // 32
  constexpr int LA = BM_ / 128;     // 1
  constexpr int ATILE = BM_ * 64;
  constexpr int AHALF = BM_ * 32;
  constexpr int BOFF = 2 * ATILE;
  __shared__ __bf16 lds[2 * BM_ * 64 + 32768];

  const int tid = threadIdx.x;
  const int l = tid & 63, w = tid >> 6;
  const int lr = l & 15, lg = l >> 4;
  const int wr = w >> 2, wc = w & 3;
  const int nwg = gridDim.x;
  const int bid = (int)blockIdx.x;
  const int swz = (bid & 7) * (nwg >> 3) + (bid >> 3);
  const int bm = swz / nbn, bn = swz % nbn;
  const int am0 = bm * BM_, bn0 = bn * 256;

  f32x4 acc[MF][4];
  const f32x4 z4 = {0.f, 0.f, 0.f, 0.f};
#pragma unroll
  for (int m = 0; m < MF; ++m)
#pragma unroll
    for (int n = 0; n < 4; ++n) acc[m][n] = z4;

  auto stageA = [&](int h, int b, int k0) {
#pragma unroll
    for (int r = 0; r < LA; ++r) {
      const int ci = r * 512 + tid;
      const int wri = ci >> 3, c8 = ci & 7;
      const int ra = (wri % SA) + (wri / SA) * (2 * SA) + h * SA;
      gld_lds16(A + (size_t)(am0 + ra) * K + k0 + ((c8 ^ (wri & 7)) << 3),
                (__bf16*)lds + b * ATILE + h * AHALF + ci * 8);
    }
  };
  auto stageB = [&](int h, int b, int k0) {
#pragma unroll
    for (int r = 0; r < 2; ++r) {
      const int ci = r * 512 + tid;
      const int wri = ci >> 3, c8 = ci & 7;
      const int rb = (wri & 31) + (wri >> 5) * 64 + h * 32;
      gld_lds16(Bt + (size_t)(bn0 + rb) * K + k0 + ((c8 ^ (wri & 7)) << 3),
                (__bf16*)lds + BOFF + b * 16384 + h * 8192 + ci * 8);
    }
  };

  const int x7 = lr & 7;
  const int aoff0 = (lr + wr * SA) * 64 + ((lg) ^ x7) * 8;
  const int aoff1 = (lr + wr * SA) * 64 + ((4 + lg) ^ x7) * 8;
  const int boff0 = BOFF + (lr + wc * 32) * 64 + ((lg) ^ x7) * 8;
  const int boff1 = BOFF + (lr + wc * 32) * 64 + ((4 + lg) ^ x7) * 8;

  const int nt = K >> 6;
  stageA(0, 0, 0);
  stageB(1, 0, 0);
  stageB(0, 0, 0);
  stageA(1, 0, 0);
  stageA(0, 1, 64);
  stageB(1, 1, 64);
  VMCNT(4);
  BAR();

  int buf = 0;
  bf16x8 afr[MH][2], bfr0[2][2], bfr1[2][2];
  for (int t = 0; t < nt; ++t) {
    const bool s1 = (t + 1 < nt);
    const bool s2 = (t + 2 < nt);
    const int nb = buf ^ 1;
    const int k1 = (t + 1) << 6;
    const int k2 = (t + 2) << 6;
    const __bf16* pa0 = lds + buf * ATILE + aoff0;
    const __bf16* pa1 = lds + buf * ATILE + aoff1;
    const __bf16* pb0 = lds + buf * 16384 + boff0;
    const __bf16* pb1 = lds + buf * 16384 + boff1;

    // ---- phase 1: read Ah0+Bh0; stage Bh0(t+1); MFMA q00 ----
#pragma unroll
    for (int i = 0; i < MH; ++i) {
      afr[i][0] = *(const bf16x8*)(pa0 + i * 1024);
      afr[i][1] = *(const bf16x8*)(pa1 + i * 1024);
    }
#pragma unroll
    for (int j = 0; j < 2; ++j) {
      bfr0[j][0] = *(const bf16x8*)(pb0 + j * 1024);
      bfr0[j][1] = *(const bf16x8*)(pb1 + j * 1024);
    }
    if (s1) stageB(0, nb, k1);
    BAR();
    __builtin_amdgcn_s_setprio(1);
#pragma unroll
    for (int kk = 0; kk < 2; ++kk)
#pragma unroll
      for (int i = 0; i < MH; ++i)
#pragma unroll
        for (int j = 0; j < 2; ++j)
          acc[i][j] = MFMA16(afr[i][kk], bfr0[j][kk], acc[i][j]);
    __builtin_amdgcn_s_setprio(0);

    // ---- phase 2: read Bh1; stage Ah1(t+1); counted gate ----
#pragma unroll
    for (int j = 0; j < 2; ++j) {
      bfr1[j][0] = *(const bf16x8*)(pb0 + 8192 + j * 1024);
      bfr1[j][1] = *(const bf16x8*)(pb1 + 8192 + j * 1024);
    }
    if (s1) {
      stageA(1, nb, k1);
      VMCNT(6);
    } else {
      VMCNT(0);
    }
    BAR();
    __builtin_amdgcn_s_setprio(1);
#pragma unroll
    for (int kk = 0; kk < 2; ++kk)
#pragma unroll
      for (int i = 0; i < MH; ++i)
#pragma unroll
        for (int j = 0; j < 2; ++j)
          acc[i][2 + j] = MFMA16(afr[i][kk], bfr1[j][kk], acc[i][2 + j]);
    __builtin_amdgcn_s_setprio(0);

    // ---- phase 3: read Ah1; stage Ah0(t+2) into live buf ----
#pragma unroll
    for (int i = 0; i < MH; ++i) {
      afr[i][0] = *(const bf16x8*)(pa0 + AHALF + i * 1024);
      afr[i][1] = *(const bf16x8*)(pa1 + AHALF + i * 1024);
    }
    if (s2) stageA(0, buf, k2);
    BAR();
    __builtin_amdgcn_s_setprio(1);
#pragma unroll
    for (int kk = 0; kk < 2; ++kk)
#pragma unroll
      for (int i = 0; i < MH; ++i)
#pragma unroll
        for (int j = 0; j < 2; ++j)
          acc[MH + i][2 + j] = MFMA16(afr[i][kk], bfr1[j][kk], acc[MH + i][2 + j]);
    __builtin_amdgcn_s_setprio(0);

    // ---- phase 4: stage Bh1(t+2); counted gate ----
    if (s2) {
      stageB(1, buf, k2);
      VMCNT(4);
    } else if (s1) {
      VMCNT(1);
    }
    BAR();
    __builtin_amdgcn_s_setprio(1);
#pragma unroll
    for (int kk = 0; kk < 2; ++kk)
#pragma unroll
      for (int i = 0; i < MH; ++i)
#pragma unroll
        for (int j = 0; j < 2; ++j)
          acc[MH + i][j] = MFMA16(afr[i][kk], bfr0[j][kk], acc[MH + i][j]);
    __builtin_amdgcn_s_setprio(0);

    buf = nb;
  }

  // ---- epilogue. C/D frag: col = lane&15, row = (lane>>4)*4 + reg ----
  if constexpr (EPI == 5) {
    const __bf16* R = (const __bf16*)Res;
    float* O = (float*)Cout;
#pragma unroll
    for (int mf = 0; mf < MF; ++mf)
#pragma unroll
      for (int nf = 0; nf < 4; ++nf)
#pragma unroll
        for (int r = 0; r < 4; ++r) {
          const int row = am0 + wr * 2 * SA + mf * 16 + lg * 4 + r;
          const int col = bn0 + wc * 64 + nf * 16 + lr;
          const size_t idx = (size_t)row * ldc + col;
          O[idx] = acc[mf][nf][r] + (float)R[idx];
        }
  } else {
    __syncthreads();
    __bf16* Ct = (__bf16*)lds;
#pragma unroll
    for (int mf = 0; mf < MF; ++mf)
#pragma unroll
      for (int nf = 0; nf < 4; ++nf)
#pragma unroll
        for (int r = 0; r < 4; ++r) {
          const int rl = wr * 2 * SA + mf * 16 + lg * 4 + r;
          const int cl = wc * 64 + nf * 16 + lr;
          float v = acc[mf][nf][r];
          if constexpr (EPI == 3) v = v / (1.f + __expf(-v));
          if constexpr (EPI == 4)
            v += ((const float*)Res)[(size_t)(am0 + rl) * D_DIM + bn0 + cl];
          Ct[rl * 256 + (((cl >> 3) ^ (rl & 7)) << 3) + (cl & 7)] = (__bf16)v;
        }
    __syncthreads();
    __bf16* O = (__bf16*)Cout;
#pragma unroll
    for (int i = 0; i < BM_ / 16; ++i) {
      const int ci = i * 512 + tid;
      const int row = ci >> 5, c8 = ci & 31;
      *(bf16x8*)(O + (size_t)(am0 + row) * ldc + bn0 + c8 * 8) =
          *(const bf16x8*)&Ct[row * 256 + ((c8 ^ (row & 7)) << 3)];
    }
  }
}

// ---------------------------------------------------------------------------
// Block-local attention — barrier-free, max-free softmax (R4, verified).
// ---------------------------------------------------------------------------
__global__ __launch_bounds__(256, 2) void attn_kernel(
    const __bf16* __restrict__ qk, const __bf16* __restrict__ vT,
    __bf16* __restrict__ out) {
  __shared__ __bf16 Pl[4][32 * 136];

  const int tid = threadIdx.x;
  const int l = tid & 63, w = tid >> 6;
  const int lr = l & 15, lg = l >> 4;
  const int bx = (int)blockIdx.x;
  const int swz = (bx & 7) * 128 + (bx >> 3);
  const int h = swz >> 6;
  const int blk = swz & 63;
  __bf16* Pw = Pl[w];

  const __bf16* qbase =
      qk + (size_t)(blk * 128 + w * 32 + lr) * QKS + h * 64 + lg * 8;
  bf16x8 qf[2][2];
#pragma unroll
  for (int m = 0; m < 2; ++m)
#pragma unroll
    for (int ks = 0; ks < 2; ++ks)
      qf[m][ks] = *(const bf16x8*)(qbase + (size_t)m * 16 * QKS + ks * 32);

  const f32x4 z4 = {0.f, 0.f, 0.f, 0.f};
  float ssum[2][4];
  f32x4 o[2][4];
#pragma unroll
  for (int m = 0; m < 2; ++m) {
#pragma unroll
    for (int r = 0; r < 4; ++r) ssum[m][r] = 0.f;
#pragma unroll
    for (int n = 0; n < 4; ++n) o[m][n] = z4;
  }

  for (int it = 0; it < 3; ++it) {
    const int kb = blk + it - 1;
    if (kb < 0 || kb >= NB_DIM) continue;
    const int rel = it - 1;
    const int kclo = (rel < 0) ? (w * 2) : 0;
    const int kchi = (rel > 0) ? (w * 2 + 2) : 8;

    f32x4 s[2][8];
    const __bf16* kbase =
        qk + (size_t)(kb * 128 + lr) * QKS + 1024 + h * 64 + lg * 8;
#pragma unroll
    for (int kc = 0; kc < 8; ++kc) {
      if (kc < kclo || kc >= kchi) continue;
      const bf16x8 k0 = *(const bf16x8*)(kbase + (size_t)kc * 16 * QKS);
      const bf16x8 k1 = *(const bf16x8*)(kbase + (size_t)kc * 16 * QKS + 32);
      s[0][kc] = MFMA16(qf[0][0], k0, z4);
      s[1][kc] = MFMA16(qf[1][0], k0, z4);
      s[0][kc] = MFMA16(qf[0][1], k1, s[0][kc]);
      s[1][kc] = MFMA16(qf[1][1], k1, s[1][kc]);
    }

#pragma unroll
    for (int m = 0; m < 2; ++m) {
#pragma unroll
      for (int r = 0; r < 4; ++r) {
        const int qi = w * 32 + m * 16 + lg * 4 + r;
        float acc_s = 0.f;
#pragma unroll
        for (int kc = 0; kc < 8; ++kc) {
          if (kc < kclo || kc >= kchi) continue;
          const int kj = kc * 16 + lr;
          float p = __expf(s[m][kc][r] * 0.125f);
          const bool valid = (rel == 0) || (rel < 0 ? (kj >= qi) : (kj <= qi));
          p = valid ? p : 0.f;
          s[m][kc][r] = p;
          acc_s += p;
        }
        ssum[m][r] += acc_s;
      }
    }

#pragma unroll
    for (int m = 0; m < 2; ++m)
#pragma unroll
      for (int kc = 0; kc < 8; ++kc) {
        if (kc < kclo || kc >= kchi) continue;
#pragma unroll
        for (int r = 0; r < 4; ++r)
          Pw[(m * 16 + lg * 4 + r) * 136 + kc * 16 + lr] = (__bf16)s[m][kc][r];
      }

    const int kslo = kclo >> 1, kshi = kchi >> 1;
    const __bf16* vbase =
        vT + (size_t)(h * 64 + lr) * T_DIM + kb * 128 + lg * 8;
#pragma unroll
    for (int ks = 0; ks < 4; ++ks) {
      if (ks < kslo || ks >= kshi) continue;
      bf16x8 pa[2];
#pragma unroll
      for (int m = 0; m < 2; ++m)
        pa[m] = *(const bf16x8*)&Pw[(m * 16 + lr) * 136 + ks * 32 + lg * 8];
#pragma unroll
      for (int n = 0; n < 4; ++n) {
        const bf16x8 vb = *(const bf16x8*)(vbase + (size_t)n * 16 * T_DIM + ks * 32);
        o[0][n] = MFMA16(pa[0], vb, o[0][n]);
        o[1][n] = MFMA16(pa[1], vb, o[1][n]);
      }
    }
  }

  float inv[2][4];
#pragma unroll
  for (int m = 0; m < 2; ++m)
#pragma unroll
    for (int r = 0; r < 4; ++r) {
      float rs = ssum[m][r];
#pragma unroll
      for (int off = 1; off < 16; off <<= 1) rs += __shfl_xor(rs, off, 64);
      inv[m][r] = __builtin_amdgcn_rcpf(rs);
    }
#pragma unroll
  for (int m = 0; m < 2; ++m)
#pragma unroll
    for (int n = 0; n < 4; ++n)
#pragma unroll
      for (int r = 0; r < 4; ++r)
        Pw[(m * 16 + lg * 4 + r) * 136 + n * 16 + lr] =
            (__bf16)(o[m][n][r] * inv[m][r]);
#pragma unroll
  for (int i = 0; i < 4; ++i) {
    const int ci = i * 64 + l;
    const int qrow = ci >> 3;
    const int c8 = (ci & 7) * 8;
    const bf16x8 vv = *(const bf16x8*)&Pw[qrow * 136 + c8];
    *(bf16x8*)(out + (size_t)(blk * 128 + w * 32 + qrow) * D_DIM + h * 64 + c8) = vv;
  }
}

// ---------------------------------------------------------------------------
extern "C" void kernel_launch(void* const* d_in, const int* in_sizes, int n_in,
                              void* d_out, int out_size, void* d_ws, size_t ws_size,
                              hipStream_t stream) {
  (void)in_sizes; (void)n_in; (void)out_size; (void)ws_size;
  const float* x      = (const float*)d_in[0];
  const float* wq     = (const float*)d_in[1];
  const float* wk     = (const float*)d_in[2];
  const float* wv     = (const float*)d_in[3];
  const float* wo     = (const float*)d_in[4];
  const float* wg     = (const float*)d_in[5];
  const float* wd     = (const float*)d_in[6];
  const float* norm_g = (const float*)d_in[7];
  const float* norm_b = (const float*)d_in[8];
  const float* ffn_g  = (const float*)d_in[9];
  const float* ffn_b  = (const float*)d_in[10];
  float* out = (float*)d_out;

  // Workspace layout (96 MB used)
  char* ws = (char*)d_ws;
  constexpr size_t MB = 1ull << 20;
  __bf16* wqkT = (__bf16*)(ws + 0 * MB);    // [2048][1024] (q rows 0-1023, k 1024-2047)
  __bf16* wvT  = (__bf16*)(ws + 4 * MB);    // [1024][1024]
  __bf16* woT  = (__bf16*)(ws + 6 * MB);
  __bf16* wgT  = (__bf16*)(ws + 8 * MB);    // [2048][1024]
  __bf16* wdT  = (__bf16*)(ws + 12 * MB);   // [1024][2048]
  __bf16* hbuf = (__bf16*)(ws + 16 * MB);   // h / attn_out / h2 (16 MB, reused)
  __bf16* qkbf = (__bf16*)(ws + 32 * MB);   // [T][2048] fused q|k (32 MB)
  __bf16* gbf  = (__bf16*)(ws + 32 * MB);   // [T][2048] gate (reuses qk)
  __bf16* vTbf = (__bf16*)(ws + 64 * MB);   // [1024][T] (16 MB)
  __bf16* x2bf = (__bf16*)(ws + 80 * MB);   // [T][D] bf16 residual (16 MB)

  // 1. all weight transposes in ONE launch
  transpose_all<<<8192, 256, 0, stream>>>(wq, wk, wv, wo, wg, wd,
                                          wqkT, wvT, woT, wgT, wdT);

  // 2. LN1 (f32 in)
  ln_kernel<float><<<8192, 256, 0, stream>>>(x, norm_g, norm_b, hbuf);

  // 3. Q and K projections as separate N=1024 launches (L2-fit regime),
  //    writing into the shared [T][2048] buffer via ldc. V transposed-out.
  gemm8<0><<<256, 512, 0, stream>>>(hbuf, wqkT, nullptr, qkbf,
                                    8192, 1024, 4, 2048);
  gemm8<0><<<256, 512, 0, stream>>>(hbuf, wqkT + 1024 * 1024, nullptr, qkbf + 1024,
                                    8192, 1024, 4, 2048);
  gemm_vt<<<dim3(8, 64), 256, 0, stream>>>(hbuf, wvT, vTbf, 8192, 1024, 1024);

  // 4. local attention -> hbuf
  attn_kernel<<<1024, 256, 0, stream>>>(qkbf, vTbf, hbuf);

  // 5. out-proj + residual: x2bf = bf16(x + attn @ wo)
  gemm8<4><<<256, 512, 0, stream>>>(hbuf, woT, x, x2bf, 8192, 1024, 4, 1024);

  // 6. LN2 (bf16 in) -> hbuf
  ln_kernel<__bf16><<<8192, 256, 0, stream>>>(x2bf, ffn_g, ffn_b, hbuf);

  // 7. gate: g = silu(h2 @ wg) as two N=1024 halves into gbf [T][2048]
  gemm8<3><<<256, 512, 0, stream>>>(hbuf, wgT, nullptr, gbf,
                                    8192, 1024, 4, 2048);
  gemm8<3><<<256, 512, 0, stream>>>(hbuf, wgT + 1024 * 1024, nullptr, gbf + 1024,
                                    8192, 1024, 4, 2048);

  // 8. down + residual: out = f32(x2bf + g @ wd)
  gemm8<5><<<256, 512, 0, stream>>>(gbf, wdT, x2bf, out, 8192, 2048, 4, 1024);
}

// Round 13
// 245.414 us; speedup vs baseline: 1.0588x; 1.0588x over previous
//
#include <hip/hip_runtime.h>
#include <cstdint>

// Problem constants
#define T_DIM 8192
#define D_DIM 1024
#define NB_DIM 64
#define QKS 2048  // row stride of fused q|k buffer

typedef __bf16 bf16x8 __attribute__((ext_vector_type(8)));
typedef __bf16 bf16x4 __attribute__((ext_vector_type(4)));
typedef float f32x4 __attribute__((ext_vector_type(4)));

#define MFMA16(a, b, c) __builtin_amdgcn_mfma_f32_16x16x32_bf16((a), (b), (c), 0, 0, 0)
#define BAR() asm volatile("s_barrier" ::: "memory")
#define VMCNT(n) asm volatile("s_waitcnt vmcnt(" #n ")" ::: "memory")

// async global->LDS, 16B per lane. LDS dest must be wave-uniform base + lane*16.
__device__ __forceinline__ void gld_lds16(const void* gsrc, void* ldst) {
  __builtin_amdgcn_global_load_lds(
      (__attribute__((address_space(1))) void*)(uintptr_t)gsrc,
      (__attribute__((address_space(3))) void*)(uintptr_t)ldst,
      16, 0, 0);
}

// ---------------------------------------------------------------------------
// Batched weight convert+transpose: 6 jobs in ONE launch (8192 blocks).
// ---------------------------------------------------------------------------
__global__ __launch_bounds__(256) void transpose_all(
    const float* __restrict__ wq, const float* __restrict__ wk,
    const float* __restrict__ wv, const float* __restrict__ wo,
    const float* __restrict__ wg, const float* __restrict__ wd,
    __bf16* __restrict__ wqkT, __bf16* __restrict__ wvT,
    __bf16* __restrict__ woT, __bf16* __restrict__ wgT,
    __bf16* __restrict__ wdT) {
  __shared__ float tile[32][33];
  const int bid = (int)blockIdx.x;
  const float* W; __bf16* Wt; int K, N, n0, k0, local;
  if (bid < 1024)      { W = wq; Wt = wqkT;            K = 1024; N = 1024; local = bid; }
  else if (bid < 2048) { W = wk; Wt = wqkT + 1048576;  K = 1024; N = 1024; local = bid - 1024; }
  else if (bid < 3072) { W = wv; Wt = wvT;             K = 1024; N = 1024; local = bid - 2048; }
  else if (bid < 4096) { W = wo; Wt = woT;             K = 1024; N = 1024; local = bid - 3072; }
  else if (bid < 6144) { W = wg; Wt = wgT;             K = 1024; N = 2048; local = bid - 4096; }
  else                 { W = wd; Wt = wdT;             K = 2048; N = 1024; local = bid - 6144; }
  if (N == 2048) { n0 = (local & 63) * 32; k0 = (local >> 6) * 32; }
  else           { n0 = (local & 31) * 32; k0 = (local >> 5) * 32; }
  const int tx = threadIdx.x & 31, ty = threadIdx.x >> 5;
#pragma unroll
  for (int i = 0; i < 32; i += 8)
    tile[ty + i][tx] = W[(size_t)(k0 + ty + i) * N + n0 + tx];
  __syncthreads();
#pragma unroll
  for (int i = 0; i < 32; i += 8)
    Wt[(size_t)(n0 + ty + i) * K + k0 + tx] = (__bf16)tile[tx][ty + i];
}

// ---------------------------------------------------------------------------
// LayerNorm: x[row][1024] (f32 or bf16) -> out bf16. One block (256) per row.
// ---------------------------------------------------------------------------
template <typename TI>
__global__ __launch_bounds__(256) void ln_kernel(
    const TI* __restrict__ x, const float* __restrict__ g,
    const float* __restrict__ b, __bf16* __restrict__ out) {
  __shared__ float red[8];
  const int row = blockIdx.x, tid = threadIdx.x;
  float v0, v1, v2, v3;
  if constexpr (sizeof(TI) == 4) {
    const float4 v = ((const float4*)(x + (size_t)row * D_DIM))[tid];
    v0 = v.x; v1 = v.y; v2 = v.z; v3 = v.w;
  } else {
    const bf16x4 v = ((const bf16x4*)(x + (size_t)row * D_DIM))[tid];
    v0 = (float)v[0]; v1 = (float)v[1]; v2 = (float)v[2]; v3 = (float)v[3];
  }
  float s = v0 + v1 + v2 + v3;
#pragma unroll
  for (int off = 32; off >= 1; off >>= 1) s += __shfl_xor(s, off, 64);
  if ((tid & 63) == 0) red[tid >> 6] = s;
  __syncthreads();
  const float mean = (red[0] + red[1] + red[2] + red[3]) * (1.0f / D_DIM);
  const float d0 = v0 - mean, d1 = v1 - mean, d2 = v2 - mean, d3 = v3 - mean;
  float ss = d0 * d0 + d1 * d1 + d2 * d2 + d3 * d3;
#pragma unroll
  for (int off = 32; off >= 1; off >>= 1) ss += __shfl_xor(ss, off, 64);
  if ((tid & 63) == 0) red[4 + (tid >> 6)] = ss;
  __syncthreads();
  const float var = (red[4] + red[5] + red[6] + red[7]) * (1.0f / D_DIM);
  const float rstd = rsqrtf(var + 1e-5f);
  const float4 gg = ((const float4*)g)[tid];
  const float4 bb = ((const float4*)b)[tid];
  bf16x4 o;
  o[0] = (__bf16)(d0 * rstd * gg.x + bb.x);
  o[1] = (__bf16)(d1 * rstd * gg.y + bb.y);
  o[2] = (__bf16)(d2 * rstd * gg.z + bb.z);
  o[3] = (__bf16)(d3 * rstd * gg.w + bb.w);
  *(bf16x4*)(out + (size_t)row * D_DIM + tid * 4) = o;
}

// ---------------------------------------------------------------------------
// gemm8 (R10-verified) — single-barrier 4 phases, t+2 staggered staging,
// counted vmcnt gates, T2 XOR swizzle both-sides, hoisted LDS addressing.
// C[M][N] = A[M][K] * Bt[N][K]^T. BN=256; BM_ in {256,128}.
// Serves: QK (256), wo (128), wg (256), down (128), and V^T via swapped
// operands (A=wvT M=1024, Bt=hbuf N=8192 -> C=vT directly, no transpose EPI).
// EPI: 0 bf16; 3 silu->bf16; 4 +Res(f32)->bf16; 5 +Res(bf16)->f32.
// ---------------------------------------------------------------------------
template <int BM_, int EPI>
__global__ __launch_bounds__(512, 2) void gemm8(
    const __bf16* __restrict__ A, const __bf16* __restrict__ Bt,
    const void* __restrict__ Res, void* __restrict__ Cout,
    int M, int N, int K, int nbn) {
  constexpr int MF = BM_ / 32;
  constexpr int MH = MF / 2;
  constexpr int SA = 8 * MF;
  constexpr int LA = BM_ / 128;
  constexpr int ATILE = BM_ * 64;
  constexpr int AHALF = BM_ * 32;
  constexpr int BOFF = 2 * ATILE;
  __shared__ __bf16 lds[2 * BM_ * 64 + 32768];

  const int tid = threadIdx.x;
  const int l = tid & 63, w = tid >> 6;
  const int lr = l & 15, lg = l >> 4;
  const int wr = w >> 2, wc = w & 3;
  const int nwg = gridDim.x;
  const int bid = (int)blockIdx.x;
  const int swz = (bid & 7) * (nwg >> 3) + (bid >> 3);
  const int bm = swz / nbn, bn = swz % nbn;
  const int am0 = bm * BM_, bn0 = bn * 256;

  f32x4 acc[MF][4];
  const f32x4 z4 = {0.f, 0.f, 0.f, 0.f};
#pragma unroll
  for (int m = 0; m < MF; ++m)
#pragma unroll
    for (int n = 0; n < 4; ++n) acc[m][n] = z4;

  auto stageA = [&](int h, int b, int k0) {
#pragma unroll
    for (int r = 0; r < LA; ++r) {
      const int ci = r * 512 + tid;
      const int wri = ci >> 3, c8 = ci & 7;
      const int ra = (wri % SA) + (wri / SA) * (2 * SA) + h * SA;
      gld_lds16(A + (size_t)(am0 + ra) * K + k0 + ((c8 ^ (wri & 7)) << 3),
                (__bf16*)lds + b * ATILE + h * AHALF + ci * 8);
    }
  };
  auto stageB = [&](int h, int b, int k0) {
#pragma unroll
    for (int r = 0; r < 2; ++r) {
      const int ci = r * 512 + tid;
      const int wri = ci >> 3, c8 = ci & 7;
      const int rb = (wri & 31) + (wri >> 5) * 64 + h * 32;
      gld_lds16(Bt + (size_t)(bn0 + rb) * K + k0 + ((c8 ^ (wri & 7)) << 3),
                (__bf16*)lds + BOFF + b * 16384 + h * 8192 + ci * 8);
    }
  };

  const int x7 = lr & 7;
  const int aoff0 = (lr + wr * SA) * 64 + ((lg) ^ x7) * 8;
  const int aoff1 = (lr + wr * SA) * 64 + ((4 + lg) ^ x7) * 8;
  const int boff0 = BOFF + (lr + wc * 32) * 64 + ((lg) ^ x7) * 8;
  const int boff1 = BOFF + (lr + wc * 32) * 64 + ((4 + lg) ^ x7) * 8;

  const int nt = K >> 6;
  stageA(0, 0, 0);
  stageB(1, 0, 0);
  stageB(0, 0, 0);
  stageA(1, 0, 0);
  stageA(0, 1, 64);
  stageB(1, 1, 64);
  if constexpr (BM_ == 256) VMCNT(6); else VMCNT(4);
  BAR();

  int buf = 0;
  bf16x8 afr[MH][2], bfr0[2][2], bfr1[2][2];
  for (int t = 0; t < nt; ++t) {
    const bool s1 = (t + 1 < nt);
    const bool s2 = (t + 2 < nt);
    const int nb = buf ^ 1;
    const int k1 = (t + 1) << 6;
    const int k2 = (t + 2) << 6;
    const __bf16* pa0 = lds + buf * ATILE + aoff0;
    const __bf16* pa1 = lds + buf * ATILE + aoff1;
    const __bf16* pb0 = lds + buf * 16384 + boff0;
    const __bf16* pb1 = lds + buf * 16384 + boff1;

    // ---- phase 1: read Ah0+Bh0; stage Bh0(t+1); MFMA q00 ----
#pragma unroll
    for (int i = 0; i < MH; ++i) {
      afr[i][0] = *(const bf16x8*)(pa0 + i * 1024);
      afr[i][1] = *(const bf16x8*)(pa1 + i * 1024);
    }
#pragma unroll
    for (int j = 0; j < 2; ++j) {
      bfr0[j][0] = *(const bf16x8*)(pb0 + j * 1024);
      bfr0[j][1] = *(const bf16x8*)(pb1 + j * 1024);
    }
    if (s1) stageB(0, nb, k1);
    BAR();
    __builtin_amdgcn_s_setprio(1);
#pragma unroll
    for (int kk = 0; kk < 2; ++kk)
#pragma unroll
      for (int i = 0; i < MH; ++i)
#pragma unroll
        for (int j = 0; j < 2; ++j)
          acc[i][j] = MFMA16(afr[i][kk], bfr0[j][kk], acc[i][j]);
    __builtin_amdgcn_s_setprio(0);

    // ---- phase 2: read Bh1; stage Ah1(t+1); counted gate ----
#pragma unroll
    for (int j = 0; j < 2; ++j) {
      bfr1[j][0] = *(const bf16x8*)(pb0 + 8192 + j * 1024);
      bfr1[j][1] = *(const bf16x8*)(pb1 + 8192 + j * 1024);
    }
    if (s1) {
      stageA(1, nb, k1);
      if constexpr (BM_ == 256) VMCNT(8); else VMCNT(6);
    } else {
      VMCNT(0);
    }
    BAR();
    __builtin_amdgcn_s_setprio(1);
#pragma unroll
    for (int kk = 0; kk < 2; ++kk)
#pragma unroll
      for (int i = 0; i < MH; ++i)
#pragma unroll
        for (int j = 0; j < 2; ++j)
          acc[i][2 + j] = MFMA16(afr[i][kk], bfr1[j][kk], acc[i][2 + j]);
    __builtin_amdgcn_s_setprio(0);

    // ---- phase 3: read Ah1; stage Ah0(t+2) into live buf ----
#pragma unroll
    for (int i = 0; i < MH; ++i) {
      afr[i][0] = *(const bf16x8*)(pa0 + AHALF + i * 1024);
      afr[i][1] = *(const bf16x8*)(pa1 + AHALF + i * 1024);
    }
    if (s2) stageA(0, buf, k2);
    BAR();
    __builtin_amdgcn_s_setprio(1);
#pragma unroll
    for (int kk = 0; kk < 2; ++kk)
#pragma unroll
      for (int i = 0; i < MH; ++i)
#pragma unroll
        for (int j = 0; j < 2; ++j)
          acc[MH + i][2 + j] = MFMA16(afr[i][kk], bfr1[j][kk], acc[MH + i][2 + j]);
    __builtin_amdgcn_s_setprio(0);

    // ---- phase 4: stage Bh1(t+2); counted gate ----
    if (s2) {
      stageB(1, buf, k2);
      if constexpr (BM_ == 256) VMCNT(6); else VMCNT(4);
    } else if (s1) {
      if constexpr (BM_ == 256) VMCNT(2); else VMCNT(1);
    }
    BAR();
    __builtin_amdgcn_s_setprio(1);
#pragma unroll
    for (int kk = 0; kk < 2; ++kk)
#pragma unroll
      for (int i = 0; i < MH; ++i)
#pragma unroll
        for (int j = 0; j < 2; ++j)
          acc[MH + i][j] = MFMA16(afr[i][kk], bfr0[j][kk], acc[MH + i][j]);
    __builtin_amdgcn_s_setprio(0);

    buf = nb;
  }

  // ---- epilogue. C/D frag: col = lane&15, row = (lane>>4)*4 + reg ----
  if constexpr (EPI == 5) {
    const __bf16* R = (const __bf16*)Res;
    float* O = (float*)Cout;
#pragma unroll
    for (int mf = 0; mf < MF; ++mf)
#pragma unroll
      for (int nf = 0; nf < 4; ++nf)
#pragma unroll
        for (int r = 0; r < 4; ++r) {
          const int row = am0 + wr * 2 * SA + mf * 16 + lg * 4 + r;
          const int col = bn0 + wc * 64 + nf * 16 + lr;
          const size_t idx = (size_t)row * N + col;
          O[idx] = acc[mf][nf][r] + (float)R[idx];
        }
  } else {
    __syncthreads();
    __bf16* Ct = (__bf16*)lds;
#pragma unroll
    for (int mf = 0; mf < MF; ++mf)
#pragma unroll
      for (int nf = 0; nf < 4; ++nf)
#pragma unroll
        for (int r = 0; r < 4; ++r) {
          const int rl = wr * 2 * SA + mf * 16 + lg * 4 + r;
          const int cl = wc * 64 + nf * 16 + lr;
          float v = acc[mf][nf][r];
          if constexpr (EPI == 3) v = v / (1.f + __expf(-v));
          if constexpr (EPI == 4)
            v += ((const float*)Res)[(size_t)(am0 + rl) * N + bn0 + cl];
          Ct[rl * 256 + (((cl >> 3) ^ (rl & 7)) << 3) + (cl & 7)] = (__bf16)v;
        }
    __syncthreads();
    __bf16* O = (__bf16*)Cout;
#pragma unroll
    for (int i = 0; i < BM_ / 16; ++i) {
      const int ci = i * 512 + tid;
      const int row = ci >> 5, c8 = ci & 31;
      *(bf16x8*)(O + (size_t)(am0 + row) * N + bn0 + c8 * 8) =
          *(const bf16x8*)&Ct[row * 256 + ((c8 ^ (row & 7)) << 3)];
    }
  }
}

// ---------------------------------------------------------------------------
// Block-local attention — barrier-free, max-free softmax (R4, verified).
// ---------------------------------------------------------------------------
__global__ __launch_bounds__(256, 2) void attn_kernel(
    const __bf16* __restrict__ qk, const __bf16* __restrict__ vT,
    __bf16* __restrict__ out) {
  __shared__ __bf16 Pl[4][32 * 136];

  const int tid = threadIdx.x;
  const int l = tid & 63, w = tid >> 6;
  const int lr = l & 15, lg = l >> 4;
  const int bx = (int)blockIdx.x;
  const int swz = (bx & 7) * 128 + (bx >> 3);
  const int h = swz >> 6;
  const int blk = swz & 63;
  __bf16* Pw = Pl[w];

  const __bf16* qbase =
      qk + (size_t)(blk * 128 + w * 32 + lr) * QKS + h * 64 + lg * 8;
  bf16x8 qf[2][2];
#pragma unroll
  for (int m = 0; m < 2; ++m)
#pragma unroll
    for (int ks = 0; ks < 2; ++ks)
      qf[m][ks] = *(const bf16x8*)(qbase + (size_t)m * 16 * QKS + ks * 32);

  const f32x4 z4 = {0.f, 0.f, 0.f, 0.f};
  float ssum[2][4];
  f32x4 o[2][4];
#pragma unroll
  for (int m = 0; m < 2; ++m) {
#pragma unroll
    for (int r = 0; r < 4; ++r) ssum[m][r] = 0.f;
#pragma unroll
    for (int n = 0; n < 4; ++n) o[m][n] = z4;
  }

  for (int it = 0; it < 3; ++it) {
    const int kb = blk + it - 1;
    if (kb < 0 || kb >= NB_DIM) continue;
    const int rel = it - 1;
    const int kclo = (rel < 0) ? (w * 2) : 0;
    const int kchi = (rel > 0) ? (w * 2 + 2) : 8;

    f32x4 s[2][8];
    const __bf16* kbase =
        qk + (size_t)(kb * 128 + lr) * QKS + 1024 + h * 64 + lg * 8;
#pragma unroll
    for (int kc = 0; kc < 8; ++kc) {
      if (kc < kclo || kc >= kchi) continue;
      const bf16x8 k0 = *(const bf16x8*)(kbase + (size_t)kc * 16 * QKS);
      const bf16x8 k1 = *(const bf16x8*)(kbase + (size_t)kc * 16 * QKS + 32);
      s[0][kc] = MFMA16(qf[0][0], k0, z4);
      s[1][kc] = MFMA16(qf[1][0], k0, z4);
      s[0][kc] = MFMA16(qf[0][1], k1, s[0][kc]);
      s[1][kc] = MFMA16(qf[1][1], k1, s[1][kc]);
    }

#pragma unroll
    for (int m = 0; m < 2; ++m) {
#pragma unroll
      for (int r = 0; r < 4; ++r) {
        const int qi = w * 32 + m * 16 + lg * 4 + r;
        float acc_s = 0.f;
#pragma unroll
        for (int kc = 0; kc < 8; ++kc) {
          if (kc < kclo || kc >= kchi) continue;
          const int kj = kc * 16 + lr;
          float p = __expf(s[m][kc][r] * 0.125f);
          const bool valid = (rel == 0) || (rel < 0 ? (kj >= qi) : (kj <= qi));
          p = valid ? p : 0.f;
          s[m][kc][r] = p;
          acc_s += p;
        }
        ssum[m][r] += acc_s;
      }
    }

#pragma unroll
    for (int m = 0; m < 2; ++m)
#pragma unroll
      for (int kc = 0; kc < 8; ++kc) {
        if (kc < kclo || kc >= kchi) continue;
#pragma unroll
        for (int r = 0; r < 4; ++r)
          Pw[(m * 16 + lg * 4 + r) * 136 + kc * 16 + lr] = (__bf16)s[m][kc][r];
      }

    const int kslo = kclo >> 1, kshi = kchi >> 1;
    const __bf16* vbase =
        vT + (size_t)(h * 64 + lr) * T_DIM + kb * 128 + lg * 8;
#pragma unroll
    for (int ks = 0; ks < 4; ++ks) {
      if (ks < kslo || ks >= kshi) continue;
      bf16x8 pa[2];
#pragma unroll
      for (int m = 0; m < 2; ++m)
        pa[m] = *(const bf16x8*)&Pw[(m * 16 + lr) * 136 + ks * 32 + lg * 8];
#pragma unroll
      for (int n = 0; n < 4; ++n) {
        const bf16x8 vb = *(const bf16x8*)(vbase + (size_t)n * 16 * T_DIM + ks * 32);
        o[0][n] = MFMA16(pa[0], vb, o[0][n]);
        o[1][n] = MFMA16(pa[1], vb, o[1][n]);
      }
    }
  }

  float inv[2][4];
#pragma unroll
  for (int m = 0; m < 2; ++m)
#pragma unroll
    for (int r = 0; r < 4; ++r) {
      float rs = ssum[m][r];
#pragma unroll
      for (int off = 1; off < 16; off <<= 1) rs += __shfl_xor(rs, off, 64);
      inv[m][r] = __builtin_amdgcn_rcpf(rs);
    }
#pragma unroll
  for (int m = 0; m < 2; ++m)
#pragma unroll
    for (int n = 0; n < 4; ++n)
#pragma unroll
      for (int r = 0; r < 4; ++r)
        Pw[(m * 16 + lg * 4 + r) * 136 + n * 16 + lr] =
            (__bf16)(o[m][n][r] * inv[m][r]);
#pragma unroll
  for (int i = 0; i < 4; ++i) {
    const int ci = i * 64 + l;
    const int qrow = ci >> 3;
    const int c8 = (ci & 7) * 8;
    const bf16x8 vv = *(const bf16x8*)&Pw[qrow * 136 + c8];
    *(bf16x8*)(out + (size_t)(blk * 128 + w * 32 + qrow) * D_DIM + h * 64 + c8) = vv;
  }
}

// ---------------------------------------------------------------------------
extern "C" void kernel_launch(void* const* d_in, const int* in_sizes, int n_in,
                              void* d_out, int out_size, void* d_ws, size_t ws_size,
                              hipStream_t stream) {
  (void)in_sizes; (void)n_in; (void)out_size; (void)ws_size;
  const float* x      = (const float*)d_in[0];
  const float* wq     = (const float*)d_in[1];
  const float* wk     = (const float*)d_in[2];
  const float* wv     = (const float*)d_in[3];
  const float* wo     = (const float*)d_in[4];
  const float* wg     = (const float*)d_in[5];
  const float* wd     = (const float*)d_in[6];
  const float* norm_g = (const float*)d_in[7];
  const float* norm_b = (const float*)d_in[8];
  const float* ffn_g  = (const float*)d_in[9];
  const float* ffn_b  = (const float*)d_in[10];
  float* out = (float*)d_out;

  // Workspace layout (96 MB used)
  char* ws = (char*)d_ws;
  constexpr size_t MB = 1ull << 20;
  __bf16* wqkT = (__bf16*)(ws + 0 * MB);    // [2048][1024] (q rows 0-1023, k 1024-2047)
  __bf16* wvT  = (__bf16*)(ws + 4 * MB);    // [1024][1024]
  __bf16* woT  = (__bf16*)(ws + 6 * MB);
  __bf16* wgT  = (__bf16*)(ws + 8 * MB);    // [2048][1024]
  __bf16* wdT  = (__bf16*)(ws + 12 * MB);   // [1024][2048]
  __bf16* hbuf = (__bf16*)(ws + 16 * MB);   // h / attn_out / h2 (16 MB, reused)
  __bf16* qkbf = (__bf16*)(ws + 32 * MB);   // [T][2048] fused q|k (32 MB)
  __bf16* gbf  = (__bf16*)(ws + 32 * MB);   // [T][2048] gate (reuses qk)
  __bf16* vTbf = (__bf16*)(ws + 64 * MB);   // [1024][T] (16 MB)
  __bf16* x2bf = (__bf16*)(ws + 80 * MB);   // [T][D] bf16 residual (16 MB)

  // 1. all weight transposes in ONE launch
  transpose_all<<<8192, 256, 0, stream>>>(wq, wk, wv, wo, wg, wd,
                                          wqkT, wvT, woT, wgT, wdT);

  // 2. LN1 (f32 in)
  ln_kernel<float><<<8192, 256, 0, stream>>>(x, norm_g, norm_b, hbuf);

  // 3. fused Q|K projection, and V^T via SWAPPED-OPERAND gemm8:
  //    vT[d][t] = sum_k wvT[d][k] * hbuf[t][k]  (A=wvT M=1024, Bt=hbuf N=8192)
  gemm8<256, 0><<<256, 512, 0, stream>>>(hbuf, wqkT, nullptr, qkbf,
                                         8192, 2048, 1024, 8);
  gemm8<128, 0><<<256, 512, 0, stream>>>(wvT, hbuf, nullptr, vTbf,
                                         1024, 8192, 1024, 32);

  // 4. local attention -> hbuf
  attn_kernel<<<1024, 256, 0, stream>>>(qkbf, vTbf, hbuf);

  // 5. out-proj + residual: x2bf = bf16(x + attn @ wo)
  gemm8<128, 4><<<256, 512, 0, stream>>>(hbuf, woT, x, x2bf, 8192, 1024, 1024, 4);

  // 6. LN2 (bf16 in) -> hbuf
  ln_kernel<__bf16><<<8192, 256, 0, stream>>>(x2bf, ffn_g, ffn_b, hbuf);

  // 7. gate: g = silu(h2 @ wg)
  gemm8<256, 3><<<256, 512, 0, stream>>>(hbuf, wgT, nullptr, gbf,
                                         8192, 2048, 1024, 8);

  // 8. down + residual: out = f32(x2bf + g @ wd)
  gemm8<128, 5><<<256, 512, 0, stream>>>(gbf, wdT, x2bf, out, 8192, 1024, 2048, 4);
}

// Round 14
// 236.923 us; speedup vs baseline: 1.0967x; 1.0358x over previous
//
#include <hip/hip_runtime.h>
#include <cstdint>

// Problem constants
#define T_DIM 8192
#define D_DIM 1024
#define NB_DIM 64
#define QKS 2048  // row stride of fused q|k buffer

typedef __bf16 bf16x8 __attribute__((ext_vector_type(8)));
typedef __bf16 bf16x4 __attribute__((ext_vector_type(4)));
typedef float f32x4 __attribute__((ext_vector_type(4)));

#define MFMA16(a, b, c) __builtin_amdgcn_mfma_f32_16x16x32_bf16((a), (b), (c), 0, 0, 0)
#define BAR() asm volatile("s_barrier" ::: "memory")
#define VMCNT(n) asm volatile("s_waitcnt vmcnt(" #n ")" ::: "memory")

// async global->LDS, 16B per lane. LDS dest must be wave-uniform base + lane*16.
__device__ __forceinline__ void gld_lds16(const void* gsrc, void* ldst) {
  __builtin_amdgcn_global_load_lds(
      (__attribute__((address_space(1))) void*)(uintptr_t)gsrc,
      (__attribute__((address_space(3))) void*)(uintptr_t)ldst,
      16, 0, 0);
}

// ---------------------------------------------------------------------------
// Batched weight convert+transpose: 6 jobs in ONE launch (8192 blocks).
// ---------------------------------------------------------------------------
__global__ __launch_bounds__(256) void transpose_all(
    const float* __restrict__ wq, const float* __restrict__ wk,
    const float* __restrict__ wv, const float* __restrict__ wo,
    const float* __restrict__ wg, const float* __restrict__ wd,
    __bf16* __restrict__ wqkT, __bf16* __restrict__ wvT,
    __bf16* __restrict__ woT, __bf16* __restrict__ wgT,
    __bf16* __restrict__ wdT) {
  __shared__ float tile[32][33];
  const int bid = (int)blockIdx.x;
  const float* W; __bf16* Wt; int K, N, n0, k0, local;
  if (bid < 1024)      { W = wq; Wt = wqkT;            K = 1024; N = 1024; local = bid; }
  else if (bid < 2048) { W = wk; Wt = wqkT + 1048576;  K = 1024; N = 1024; local = bid - 1024; }
  else if (bid < 3072) { W = wv; Wt = wvT;             K = 1024; N = 1024; local = bid - 2048; }
  else if (bid < 4096) { W = wo; Wt = woT;             K = 1024; N = 1024; local = bid - 3072; }
  else if (bid < 6144) { W = wg; Wt = wgT;             K = 1024; N = 2048; local = bid - 4096; }
  else                 { W = wd; Wt = wdT;             K = 2048; N = 1024; local = bid - 6144; }
  if (N == 2048) { n0 = (local & 63) * 32; k0 = (local >> 6) * 32; }
  else           { n0 = (local & 31) * 32; k0 = (local >> 5) * 32; }
  const int tx = threadIdx.x & 31, ty = threadIdx.x >> 5;
#pragma unroll
  for (int i = 0; i < 32; i += 8)
    tile[ty + i][tx] = W[(size_t)(k0 + ty + i) * N + n0 + tx];
  __syncthreads();
#pragma unroll
  for (int i = 0; i < 32; i += 8)
    Wt[(size_t)(n0 + ty + i) * K + k0 + tx] = (__bf16)tile[tx][ty + i];
}

// ---------------------------------------------------------------------------
// LayerNorm: x[row][1024] (f32 or bf16) -> out bf16. One block (256) per row.
// ---------------------------------------------------------------------------
template <typename TI>
__global__ __launch_bounds__(256) void ln_kernel(
    const TI* __restrict__ x, const float* __restrict__ g,
    const float* __restrict__ b, __bf16* __restrict__ out) {
  __shared__ float red[8];
  const int row = blockIdx.x, tid = threadIdx.x;
  float v0, v1, v2, v3;
  if constexpr (sizeof(TI) == 4) {
    const float4 v = ((const float4*)(x + (size_t)row * D_DIM))[tid];
    v0 = v.x; v1 = v.y; v2 = v.z; v3 = v.w;
  } else {
    const bf16x4 v = ((const bf16x4*)(x + (size_t)row * D_DIM))[tid];
    v0 = (float)v[0]; v1 = (float)v[1]; v2 = (float)v[2]; v3 = (float)v[3];
  }
  float s = v0 + v1 + v2 + v3;
#pragma unroll
  for (int off = 32; off >= 1; off >>= 1) s += __shfl_xor(s, off, 64);
  if ((tid & 63) == 0) red[tid >> 6] = s;
  __syncthreads();
  const float mean = (red[0] + red[1] + red[2] + red[3]) * (1.0f / D_DIM);
  const float d0 = v0 - mean, d1 = v1 - mean, d2 = v2 - mean, d3 = v3 - mean;
  float ss = d0 * d0 + d1 * d1 + d2 * d2 + d3 * d3;
#pragma unroll
  for (int off = 32; off >= 1; off >>= 1) ss += __shfl_xor(ss, off, 64);
  if ((tid & 63) == 0) red[4 + (tid >> 6)] = ss;
  __syncthreads();
  const float var = (red[4] + red[5] + red[6] + red[7]) * (1.0f / D_DIM);
  const float rstd = rsqrtf(var + 1e-5f);
  const float4 gg = ((const float4*)g)[tid];
  const float4 bb = ((const float4*)b)[tid];
  bf16x4 o;
  o[0] = (__bf16)(d0 * rstd * gg.x + bb.x);
  o[1] = (__bf16)(d1 * rstd * gg.y + bb.y);
  o[2] = (__bf16)(d2 * rstd * gg.z + bb.z);
  o[3] = (__bf16)(d3 * rstd * gg.w + bb.w);
  *(bf16x4*)(out + (size_t)row * D_DIM + tid * 4) = o;
}

// ---------------------------------------------------------------------------
// gemm8 (R10-verified) — single-barrier 4 phases, t+2 staggered staging,
// counted vmcnt gates, T2 XOR swizzle both-sides, hoisted LDS addressing.
// C[M][N] = A[M][K] * Bt[N][K]^T. BN=256; BM_ in {256,128}.
// Serves: QK (256), wo (128), wg (256), down (128), and V^T via swapped
// operands (A=wvT M=1024, Bt=hbuf N=8192 -> C=vT directly).
// EPI: 0 bf16; 3 silu->bf16; 4 +Res(f32)->bf16; 5 +Res(bf16)->f32.
// ---------------------------------------------------------------------------
template <int BM_, int EPI>
__global__ __launch_bounds__(512, 2) void gemm8(
    const __bf16* __restrict__ A, const __bf16* __restrict__ Bt,
    const void* __restrict__ Res, void* __restrict__ Cout,
    int M, int N, int K, int nbn) {
  constexpr int MF = BM_ / 32;
  constexpr int MH = MF / 2;
  constexpr int SA = 8 * MF;
  constexpr int LA = BM_ / 128;
  constexpr int ATILE = BM_ * 64;
  constexpr int AHALF = BM_ * 32;
  constexpr int BOFF = 2 * ATILE;
  __shared__ __bf16 lds[2 * BM_ * 64 + 32768];

  const int tid = threadIdx.x;
  const int l = tid & 63, w = tid >> 6;
  const int lr = l & 15, lg = l >> 4;
  const int wr = w >> 2, wc = w & 3;
  const int nwg = gridDim.x;
  const int bid = (int)blockIdx.x;
  const int swz = (bid & 7) * (nwg >> 3) + (bid >> 3);
  const int bm = swz / nbn, bn = swz % nbn;
  const int am0 = bm * BM_, bn0 = bn * 256;

  f32x4 acc[MF][4];
  const f32x4 z4 = {0.f, 0.f, 0.f, 0.f};
#pragma unroll
  for (int m = 0; m < MF; ++m)
#pragma unroll
    for (int n = 0; n < 4; ++n) acc[m][n] = z4;

  auto stageA = [&](int h, int b, int k0) {
#pragma unroll
    for (int r = 0; r < LA; ++r) {
      const int ci = r * 512 + tid;
      const int wri = ci >> 3, c8 = ci & 7;
      const int ra = (wri % SA) + (wri / SA) * (2 * SA) + h * SA;
      gld_lds16(A + (size_t)(am0 + ra) * K + k0 + ((c8 ^ (wri & 7)) << 3),
                (__bf16*)lds + b * ATILE + h * AHALF + ci * 8);
    }
  };
  auto stageB = [&](int h, int b, int k0) {
#pragma unroll
    for (int r = 0; r < 2; ++r) {
      const int ci = r * 512 + tid;
      const int wri = ci >> 3, c8 = ci & 7;
      const int rb = (wri & 31) + (wri >> 5) * 64 + h * 32;
      gld_lds16(Bt + (size_t)(bn0 + rb) * K + k0 + ((c8 ^ (wri & 7)) << 3),
                (__bf16*)lds + BOFF + b * 16384 + h * 8192 + ci * 8);
    }
  };

  const int x7 = lr & 7;
  const int aoff0 = (lr + wr * SA) * 64 + ((lg) ^ x7) * 8;
  const int aoff1 = (lr + wr * SA) * 64 + ((4 + lg) ^ x7) * 8;
  const int boff0 = BOFF + (lr + wc * 32) * 64 + ((lg) ^ x7) * 8;
  const int boff1 = BOFF + (lr + wc * 32) * 64 + ((4 + lg) ^ x7) * 8;

  const int nt = K >> 6;
  stageA(0, 0, 0);
  stageB(1, 0, 0);
  stageB(0, 0, 0);
  stageA(1, 0, 0);
  stageA(0, 1, 64);
  stageB(1, 1, 64);
  if constexpr (BM_ == 256) VMCNT(6); else VMCNT(4);
  BAR();

  int buf = 0;
  bf16x8 afr[MH][2], bfr0[2][2], bfr1[2][2];
  for (int t = 0; t < nt; ++t) {
    const bool s1 = (t + 1 < nt);
    const bool s2 = (t + 2 < nt);
    const int nb = buf ^ 1;
    const int k1 = (t + 1) << 6;
    const int k2 = (t + 2) << 6;
    const __bf16* pa0 = lds + buf * ATILE + aoff0;
    const __bf16* pa1 = lds + buf * ATILE + aoff1;
    const __bf16* pb0 = lds + buf * 16384 + boff0;
    const __bf16* pb1 = lds + buf * 16384 + boff1;

    // ---- phase 1: read Ah0+Bh0; stage Bh0(t+1); MFMA q00 ----
#pragma unroll
    for (int i = 0; i < MH; ++i) {
      afr[i][0] = *(const bf16x8*)(pa0 + i * 1024);
      afr[i][1] = *(const bf16x8*)(pa1 + i * 1024);
    }
#pragma unroll
    for (int j = 0; j < 2; ++j) {
      bfr0[j][0] = *(const bf16x8*)(pb0 + j * 1024);
      bfr0[j][1] = *(const bf16x8*)(pb1 + j * 1024);
    }
    if (s1) stageB(0, nb, k1);
    BAR();
    __builtin_amdgcn_s_setprio(1);
#pragma unroll
    for (int kk = 0; kk < 2; ++kk)
#pragma unroll
      for (int i = 0; i < MH; ++i)
#pragma unroll
        for (int j = 0; j < 2; ++j)
          acc[i][j] = MFMA16(afr[i][kk], bfr0[j][kk], acc[i][j]);
    __builtin_amdgcn_s_setprio(0);

    // ---- phase 2: read Bh1; stage Ah1(t+1); counted gate ----
#pragma unroll
    for (int j = 0; j < 2; ++j) {
      bfr1[j][0] = *(const bf16x8*)(pb0 + 8192 + j * 1024);
      bfr1[j][1] = *(const bf16x8*)(pb1 + 8192 + j * 1024);
    }
    if (s1) {
      stageA(1, nb, k1);
      if constexpr (BM_ == 256) VMCNT(8); else VMCNT(6);
    } else {
      VMCNT(0);
    }
    BAR();
    __builtin_amdgcn_s_setprio(1);
#pragma unroll
    for (int kk = 0; kk < 2; ++kk)
#pragma unroll
      for (int i = 0; i < MH; ++i)
#pragma unroll
        for (int j = 0; j < 2; ++j)
          acc[i][2 + j] = MFMA16(afr[i][kk], bfr1[j][kk], acc[i][2 + j]);
    __builtin_amdgcn_s_setprio(0);

    // ---- phase 3: read Ah1; stage Ah0(t+2) into live buf ----
#pragma unroll
    for (int i = 0; i < MH; ++i) {
      afr[i][0] = *(const bf16x8*)(pa0 + AHALF + i * 1024);
      afr[i][1] = *(const bf16x8*)(pa1 + AHALF + i * 1024);
    }
    if (s2) stageA(0, buf, k2);
    BAR();
    __builtin_amdgcn_s_setprio(1);
#pragma unroll
    for (int kk = 0; kk < 2; ++kk)
#pragma unroll
      for (int i = 0; i < MH; ++i)
#pragma unroll
        for (int j = 0; j < 2; ++j)
          acc[MH + i][2 + j] = MFMA16(afr[i][kk], bfr1[j][kk], acc[MH + i][2 + j]);
    __builtin_amdgcn_s_setprio(0);

    // ---- phase 4: stage Bh1(t+2); counted gate ----
    if (s2) {
      stageB(1, buf, k2);
      if constexpr (BM_ == 256) VMCNT(6); else VMCNT(4);
    } else if (s1) {
      if constexpr (BM_ == 256) VMCNT(2); else VMCNT(1);
    }
    BAR();
    __builtin_amdgcn_s_setprio(1);
#pragma unroll
    for (int kk = 0; kk < 2; ++kk)
#pragma unroll
      for (int i = 0; i < MH; ++i)
#pragma unroll
        for (int j = 0; j < 2; ++j)
          acc[MH + i][j] = MFMA16(afr[i][kk], bfr0[j][kk], acc[MH + i][j]);
    __builtin_amdgcn_s_setprio(0);

    buf = nb;
  }

  // ---- epilogue. C/D frag: col = lane&15, row = (lane>>4)*4 + reg ----
  if constexpr (EPI == 5) {
    const __bf16* R = (const __bf16*)Res;
    float* O = (float*)Cout;
#pragma unroll
    for (int mf = 0; mf < MF; ++mf)
#pragma unroll
      for (int nf = 0; nf < 4; ++nf)
#pragma unroll
        for (int r = 0; r < 4; ++r) {
          const int row = am0 + wr * 2 * SA + mf * 16 + lg * 4 + r;
          const int col = bn0 + wc * 64 + nf * 16 + lr;
          const size_t idx = (size_t)row * N + col;
          O[idx] = acc[mf][nf][r] + (float)R[idx];
        }
  } else {
    __syncthreads();
    __bf16* Ct = (__bf16*)lds;
#pragma unroll
    for (int mf = 0; mf < MF; ++mf)
#pragma unroll
      for (int nf = 0; nf < 4; ++nf)
#pragma unroll
        for (int r = 0; r < 4; ++r) {
          const int rl = wr * 2 * SA + mf * 16 + lg * 4 + r;
          const int cl = wc * 64 + nf * 16 + lr;
          float v = acc[mf][nf][r];
          if constexpr (EPI == 3) v = v / (1.f + __expf(-v));
          if constexpr (EPI == 4)
            v += ((const float*)Res)[(size_t)(am0 + rl) * N + bn0 + cl];
          Ct[rl * 256 + (((cl >> 3) ^ (rl & 7)) << 3) + (cl & 7)] = (__bf16)v;
        }
    __syncthreads();
    __bf16* O = (__bf16*)Cout;
#pragma unroll
    for (int i = 0; i < BM_ / 16; ++i) {
      const int ci = i * 512 + tid;
      const int row = ci >> 5, c8 = ci & 31;
      *(bf16x8*)(O + (size_t)(am0 + row) * N + bn0 + c8 * 8) =
          *(const bf16x8*)&Ct[row * 256 + ((c8 ^ (row & 7)) << 3)];
    }
  }
}

// ---------------------------------------------------------------------------
// Block-local attention v6 — ONE WAVE PER BLOCK (max TLP; waves were already
// independent in the 4-wave version: no barriers, per-wave LDS regions).
// 4096 blocks x 64 thr; LDS 8.7 KB/block -> ~18 blocks/CU by LDS, ~5/SIMD by
// VGPR (~96): resident waves/CU rises 16 -> ~20-24. launch_bounds(64,2)
// leaves VGPR allocator free (R3's (64,4) cap at 64 caused the spill storm).
// Max-free softmax (scores O(1)-bounded), per-lane deferred denominator.
// ---------------------------------------------------------------------------
__global__ __launch_bounds__(64, 2) void attn_kernel(
    const __bf16* __restrict__ qk, const __bf16* __restrict__ vT,
    __bf16* __restrict__ out) {
  __shared__ __bf16 Pw[32 * 136];  // 8704 B

  const int l = (int)threadIdx.x;
  const int lr = l & 15, lg = l >> 4;
  // XCD-chunked swizzle: each XCD gets 512 consecutive swz = 2 heads
  const int bx = (int)blockIdx.x;
  const int swz = (bx & 7) * 512 + (bx >> 3);
  const int h = swz >> 8;
  const int blk = (swz >> 2) & 63;
  const int w = swz & 3;

  const __bf16* qbase =
      qk + (size_t)(blk * 128 + w * 32 + lr) * QKS + h * 64 + lg * 8;
  bf16x8 qf[2][2];
#pragma unroll
  for (int m = 0; m < 2; ++m)
#pragma unroll
    for (int ks = 0; ks < 2; ++ks)
      qf[m][ks] = *(const bf16x8*)(qbase + (size_t)m * 16 * QKS + ks * 32);

  const f32x4 z4 = {0.f, 0.f, 0.f, 0.f};
  float ssum[2][4];
  f32x4 o[2][4];
#pragma unroll
  for (int m = 0; m < 2; ++m) {
#pragma unroll
    for (int r = 0; r < 4; ++r) ssum[m][r] = 0.f;
#pragma unroll
    for (int n = 0; n < 4; ++n) o[m][n] = z4;
  }

  for (int it = 0; it < 3; ++it) {
    const int kb = blk + it - 1;
    if (kb < 0 || kb >= NB_DIM) continue;
    const int rel = it - 1;
    const int kclo = (rel < 0) ? (w * 2) : 0;
    const int kchi = (rel > 0) ? (w * 2 + 2) : 8;

    f32x4 s[2][8];
    const __bf16* kbase =
        qk + (size_t)(kb * 128 + lr) * QKS + 1024 + h * 64 + lg * 8;
#pragma unroll
    for (int kc = 0; kc < 8; ++kc) {
      if (kc < kclo || kc >= kchi) continue;
      const bf16x8 k0 = *(const bf16x8*)(kbase + (size_t)kc * 16 * QKS);
      const bf16x8 k1 = *(const bf16x8*)(kbase + (size_t)kc * 16 * QKS + 32);
      s[0][kc] = MFMA16(qf[0][0], k0, z4);
      s[1][kc] = MFMA16(qf[1][0], k0, z4);
      s[0][kc] = MFMA16(qf[0][1], k1, s[0][kc]);
      s[1][kc] = MFMA16(qf[1][1], k1, s[1][kc]);
    }

#pragma unroll
    for (int m = 0; m < 2; ++m) {
#pragma unroll
      for (int r = 0; r < 4; ++r) {
        const int qi = w * 32 + m * 16 + lg * 4 + r;
        float acc_s = 0.f;
#pragma unroll
        for (int kc = 0; kc < 8; ++kc) {
          if (kc < kclo || kc >= kchi) continue;
          const int kj = kc * 16 + lr;
          float p = __expf(s[m][kc][r] * 0.125f);
          const bool valid = (rel == 0) || (rel < 0 ? (kj >= qi) : (kj <= qi));
          p = valid ? p : 0.f;
          s[m][kc][r] = p;
          acc_s += p;
        }
        ssum[m][r] += acc_s;
      }
    }

#pragma unroll
    for (int m = 0; m < 2; ++m)
#pragma unroll
      for (int kc = 0; kc < 8; ++kc) {
        if (kc < kclo || kc >= kchi) continue;
#pragma unroll
        for (int r = 0; r < 4; ++r)
          Pw[(m * 16 + lg * 4 + r) * 136 + kc * 16 + lr] = (__bf16)s[m][kc][r];
      }

    const int kslo = kclo >> 1, kshi = kchi >> 1;
    const __bf16* vbase =
        vT + (size_t)(h * 64 + lr) * T_DIM + kb * 128 + lg * 8;
#pragma unroll
    for (int ks = 0; ks < 4; ++ks) {
      if (ks < kslo || ks >= kshi) continue;
      bf16x8 pa[2];
#pragma unroll
      for (int m = 0; m < 2; ++m)
        pa[m] = *(const bf16x8*)&Pw[(m * 16 + lr) * 136 + ks * 32 + lg * 8];
#pragma unroll
      for (int n = 0; n < 4; ++n) {
        const bf16x8 vb = *(const bf16x8*)(vbase + (size_t)n * 16 * T_DIM + ks * 32);
        o[0][n] = MFMA16(pa[0], vb, o[0][n]);
        o[1][n] = MFMA16(pa[1], vb, o[1][n]);
      }
    }
  }

  float inv[2][4];
#pragma unroll
  for (int m = 0; m < 2; ++m)
#pragma unroll
    for (int r = 0; r < 4; ++r) {
      float rs = ssum[m][r];
#pragma unroll
      for (int off = 1; off < 16; off <<= 1) rs += __shfl_xor(rs, off, 64);
      inv[m][r] = __builtin_amdgcn_rcpf(rs);
    }
#pragma unroll
  for (int m = 0; m < 2; ++m)
#pragma unroll
    for (int n = 0; n < 4; ++n)
#pragma unroll
      for (int r = 0; r < 4; ++r)
        Pw[(m * 16 + lg * 4 + r) * 136 + n * 16 + lr] =
            (__bf16)(o[m][n][r] * inv[m][r]);
#pragma unroll
  for (int i = 0; i < 4; ++i) {
    const int ci = i * 64 + l;
    const int qrow = ci >> 3;
    const int c8 = (ci & 7) * 8;
    const bf16x8 vv = *(const bf16x8*)&Pw[qrow * 136 + c8];
    *(bf16x8*)(out + (size_t)(blk * 128 + w * 32 + qrow) * D_DIM + h * 64 + c8) = vv;
  }
}

// ---------------------------------------------------------------------------
extern "C" void kernel_launch(void* const* d_in, const int* in_sizes, int n_in,
                              void* d_out, int out_size, void* d_ws, size_t ws_size,
                              hipStream_t stream) {
  (void)in_sizes; (void)n_in; (void)out_size; (void)ws_size;
  const float* x      = (const float*)d_in[0];
  const float* wq     = (const float*)d_in[1];
  const float* wk     = (const float*)d_in[2];
  const float* wv     = (const float*)d_in[3];
  const float* wo     = (const float*)d_in[4];
  const float* wg     = (const float*)d_in[5];
  const float* wd     = (const float*)d_in[6];
  const float* norm_g = (const float*)d_in[7];
  const float* norm_b = (const float*)d_in[8];
  const float* ffn_g  = (const float*)d_in[9];
  const float* ffn_b  = (const float*)d_in[10];
  float* out = (float*)d_out;

  // Workspace layout (96 MB used)
  char* ws = (char*)d_ws;
  constexpr size_t MB = 1ull << 20;
  __bf16* wqkT = (__bf16*)(ws + 0 * MB);    // [2048][1024] (q rows 0-1023, k 1024-2047)
  __bf16* wvT  = (__bf16*)(ws + 4 * MB);    // [1024][1024]
  __bf16* woT  = (__bf16*)(ws + 6 * MB);
  __bf16* wgT  = (__bf16*)(ws + 8 * MB);    // [2048][1024]
  __bf16* wdT  = (__bf16*)(ws + 12 * MB);   // [1024][2048]
  __bf16* hbuf = (__bf16*)(ws + 16 * MB);   // h / attn_out / h2 (16 MB, reused)
  __bf16* qkbf = (__bf16*)(ws + 32 * MB);   // [T][2048] fused q|k (32 MB)
  __bf16* gbf  = (__bf16*)(ws + 32 * MB);   // [T][2048] gate (reuses qk)
  __bf16* vTbf = (__bf16*)(ws + 64 * MB);   // [1024][T] (16 MB)
  __bf16* x2bf = (__bf16*)(ws + 80 * MB);   // [T][D] bf16 residual (16 MB)

  // 1. all weight transposes in ONE launch
  transpose_all<<<8192, 256, 0, stream>>>(wq, wk, wv, wo, wg, wd,
                                          wqkT, wvT, woT, wgT, wdT);

  // 2. LN1 (f32 in)
  ln_kernel<float><<<8192, 256, 0, stream>>>(x, norm_g, norm_b, hbuf);

  // 3. fused Q|K projection, and V^T via swapped-operand gemm8
  gemm8<256, 0><<<256, 512, 0, stream>>>(hbuf, wqkT, nullptr, qkbf,
                                         8192, 2048, 1024, 8);
  gemm8<128, 0><<<256, 512, 0, stream>>>(wvT, hbuf, nullptr, vTbf,
                                         1024, 8192, 1024, 32);

  // 4. local attention -> hbuf (1 wave per block)
  attn_kernel<<<4096, 64, 0, stream>>>(qkbf, vTbf, hbuf);

  // 5. out-proj + residual: x2bf = bf16(x + attn @ wo)
  gemm8<128, 4><<<256, 512, 0, stream>>>(hbuf, woT, x, x2bf, 8192, 1024, 1024, 4);

  // 6. LN2 (bf16 in) -> hbuf
  ln_kernel<__bf16><<<8192, 256, 0, stream>>>(x2bf, ffn_g, ffn_b, hbuf);

  // 7. gate: g = silu(h2 @ wg)
  gemm8<256, 3><<<256, 512, 0, stream>>>(hbuf, wgT, nullptr, gbf,
                                         8192, 2048, 1024, 8);

  // 8. down + residual: out = f32(x2bf + g @ wd)
  gemm8<128, 5><<<256, 512, 0, stream>>>(gbf, wdT, x2bf, out, 8192, 1024, 2048, 4);
}